// Round 1
// baseline (1839.892 us; speedup 1.0000x reference)
//
#include <hip/hip_runtime.h>
#include <stdint.h>

typedef unsigned short u16;
typedef unsigned int u32;
typedef __bf16 bf16x8 __attribute__((ext_vector_type(8)));
typedef float floatx4 __attribute__((ext_vector_type(4)));

#define NEG_INF_F (-10000000.0f)

__device__ __forceinline__ float bf2f(u16 u) {
    union { u32 u; float f; } x; x.u = ((u32)u) << 16; return x.f;
}
__device__ __forceinline__ u16 f2bf(float f) {
    union { float f; u32 u; } x; x.f = f;
    u32 r = x.u + 0x7fffu + ((x.u >> 16) & 1u);   // RNE
    return (u16)(r >> 16);
}

__device__ __forceinline__ void async_cp16(const void* g, void* l) {
    __builtin_amdgcn_global_load_lds(
        (const __attribute__((address_space(1))) void*)g,
        (__attribute__((address_space(3))) void*)l, 16, 0, 0);
}

// ---------------------------------------------------------------------------
// BT GEMM: C[m,n] = sum_k A[m,k] * B[n,k]   (both operands row-major over k)
// 128x128 tile, 256 threads (4 waves in 2x2), mfma_f32_16x16x32_bf16,
// global_load_lds width-16 staging, BK=32, 2-barrier K-loop (m97 structure).
// ---------------------------------------------------------------------------
enum { EPI_QKV = 0, EPI_LOGITS = 1, EPI_CTX = 2, EPI_MLP = 3, EPI_OUT = 4 };

template <int EPI>
__global__ __launch_bounds__(256) void gemm_bt(
    const u16* __restrict__ A, int lda, long long aBatch,
    const u16* __restrict__ B, int ldb, long long bBatch,
    void* __restrict__ Cv, int ldc, long long cBatch,
    int K,
    const float* __restrict__ bias,
    float* __restrict__ xbuf,          // EPI_MLP: residual stream (read+write)
    const u16* __restrict__ ctxb,      // EPI_MLP: ctx bf16 (read)
    u16* __restrict__ xb,              // EPI_MLP: bf16 copy of new x (write)
    float scale)
{
    __shared__ __align__(16) u16 sA[128 * 32];
    __shared__ __align__(16) u16 sB[128 * 32];

    const int tid  = threadIdx.x;
    const int wave = tid >> 6;
    const int lane = tid & 63;
    const int bz   = blockIdx.z;

    const u16* Ab = A + (long long)bz * aBatch + (long long)(blockIdx.y * 128) * lda;
    const u16* Bb = B + (long long)bz * bBatch + (long long)(blockIdx.x * 128) * ldb;

    const int wm = wave >> 1, wn = wave & 1;
    // LDS fragment read offsets (elements): row*32 + quad*8
    const int arow = (64 * wm + (lane & 15)) * 32 + ((lane >> 4) << 3);
    const int brow = (64 * wn + (lane & 15)) * 32 + ((lane >> 4) << 3);

    // staging: 8 wave-calls of 64 lanes x 16B fill 128x32 bf16 contiguously
    const int call0 = wave * 2, call1 = wave * 2 + 1;
    const int srow0 = call0 * 16 + (lane >> 2);
    const int srow1 = call1 * 16 + (lane >> 2);
    const int skp   = (lane & 3) << 3;

    floatx4 zero = {0.f, 0.f, 0.f, 0.f};
    floatx4 acc[4][4];
#pragma unroll
    for (int i = 0; i < 4; ++i)
#pragma unroll
        for (int j = 0; j < 4; ++j) acc[i][j] = zero;

    for (int k0 = 0; k0 < K; k0 += 32) {
        async_cp16(Ab + (long long)srow0 * lda + k0 + skp, &sA[call0 * 512 + lane * 8]);
        async_cp16(Ab + (long long)srow1 * lda + k0 + skp, &sA[call1 * 512 + lane * 8]);
        async_cp16(Bb + (long long)srow0 * ldb + k0 + skp, &sB[call0 * 512 + lane * 8]);
        async_cp16(Bb + (long long)srow1 * ldb + k0 + skp, &sB[call1 * 512 + lane * 8]);
        __syncthreads();   // compiler drains vmcnt(0) before s_barrier

        bf16x8 af[4], bf[4];
#pragma unroll
        for (int mi = 0; mi < 4; ++mi) af[mi] = *(const bf16x8*)&sA[arow + mi * 512];
#pragma unroll
        for (int ni = 0; ni < 4; ++ni) bf[ni] = *(const bf16x8*)&sB[brow + ni * 512];
#pragma unroll
        for (int mi = 0; mi < 4; ++mi)
#pragma unroll
            for (int ni = 0; ni < 4; ++ni)
                acc[mi][ni] = __builtin_amdgcn_mfma_f32_16x16x32_bf16(
                    af[mi], bf[ni], acc[mi][ni], 0, 0, 0);
        __syncthreads();
    }

    // epilogue: C/D layout col = lane&15, row = (lane>>4)*4 + reg  [m89-verified]
    const int m0 = blockIdx.y * 128 + 64 * wm + ((lane >> 4) << 2);
    const int n0 = blockIdx.x * 128 + 64 * wn + (lane & 15);
#pragma unroll
    for (int mi = 0; mi < 4; ++mi) {
#pragma unroll
        for (int ni = 0; ni < 4; ++ni) {
            const int gn = n0 + ni * 16;
#pragma unroll
            for (int r = 0; r < 4; ++r) {
                const int gm = m0 + mi * 16 + r;
                float v = acc[mi][ni][r];
                if constexpr (EPI == EPI_QKV) {
                    v += bias[gn];
                    ((u16*)Cv)[(long long)bz * cBatch + (long long)gm * ldc + gn] = f2bf(v);
                } else if constexpr (EPI == EPI_LOGITS) {
                    v = v * scale + (gm > gn ? NEG_INF_F : 0.0f);  // m=key, n=query
                    ((float*)Cv)[(long long)bz * cBatch + (long long)gm * ldc + gn] = v;
                } else if constexpr (EPI == EPI_CTX) {
                    ((u16*)Cv)[(long long)bz * cBatch + (long long)gm * ldc + gn] = f2bf(v);
                } else if constexpr (EPI == EPI_MLP) {
                    const long long idx = (long long)gm * ldc + gn;
                    v += bias[gn];
                    v = fmaxf(v, 0.0f);
                    float xv = xbuf[idx] + bf2f(ctxb[idx]) + v;  // x + ctx + relu(mlp)
                    xbuf[idx] = xv;
                    xb[idx]   = f2bf(xv);
                } else {  // EPI_OUT
                    v += bias[gn];
                    ((float*)Cv)[(long long)gm * ldc + gn] = v;
                }
            }
        }
    }
}

// ---------------------------------------------------------------------------
// Tiled transpose -> bf16. in: R x C (row-major, stride inStride), out[c][r].
// Grid: (C/64, R/64, batches), block (64,4). LDS pad 65 -> conflict-free.
// ---------------------------------------------------------------------------
template <typename Tin>
__global__ void transpose_bf16(const Tin* __restrict__ in, int inStride, long long inBatch,
                               u16* __restrict__ out, int outStride, long long outBatch)
{
    __shared__ float tile[64][65];
    const Tin* ib = in + (long long)blockIdx.z * inBatch;
    u16* ob       = out + (long long)blockIdx.z * outBatch;
    const int r0 = blockIdx.y * 64, c0 = blockIdx.x * 64;
    const int x = threadIdx.x, y = threadIdx.y;
#pragma unroll
    for (int j = 0; j < 16; ++j) {
        int r = y + j * 4;
        float v;
        if constexpr (sizeof(Tin) == 2)
            v = bf2f(((const u16*)ib)[(long long)(r0 + r) * inStride + c0 + x]);
        else
            v = ((const float*)ib)[(long long)(r0 + r) * inStride + c0 + x];
        tile[r][x] = v;
    }
    __syncthreads();
#pragma unroll
    for (int j = 0; j < 16; ++j) {
        int r = y + j * 4;
        ob[(long long)(c0 + r) * outStride + r0 + x] = f2bf(tile[x][r]);
    }
}

// ---------------------------------------------------------------------------
// Column softmax over key axis (rows), in-place on [S,S] f32 tiles.
// Grid (S/64, B), block (64,16): thread (x,ky) owns column q = blk*64+x,
// strided k-slice; LDS combine of 16 online-softmax partials.
// ---------------------------------------------------------------------------
__global__ __launch_bounds__(1024) void softmax_cols(float* __restrict__ logits,
                                                     long long batchStride)
{
    __shared__ float sm[16][64], sl[16][64], sfm[64], sfi[64];
    float* base = logits + (long long)blockIdx.y * batchStride;
    const int x = threadIdx.x, ky = threadIdx.y;
    const int q = blockIdx.x * 64 + x;

    float m = -3.4e38f, l = 0.f;
    for (int k = ky; k < 1024; k += 16) {
        float v  = base[(long long)k * 1024 + q];
        float mn = fmaxf(m, v);
        l = l * __expf(m - mn) + __expf(v - mn);
        m = mn;
    }
    sm[ky][x] = m;
    sl[ky][x] = l;
    __syncthreads();
    if (ky == 0) {
        float M = -3.4e38f;
        for (int j = 0; j < 16; ++j) M = fmaxf(M, sm[j][x]);
        float L = 0.f;
        for (int j = 0; j < 16; ++j) L += sl[j][x] * __expf(sm[j][x] - M);
        sfm[x] = M;
        sfi[x] = 1.0f / L;
    }
    __syncthreads();
    const float M = sfm[x], inv = sfi[x];
    for (int k = ky; k < 1024; k += 16) {
        long long idx = (long long)k * 1024 + q;
        base[idx] = __expf(base[idx] - M) * inv;
    }
}

// ---------------------------------------------------------------------------
__global__ void embed_kernel(const int* __restrict__ tok, const float* __restrict__ emb,
                             float* __restrict__ x, u16* __restrict__ xb)
{
    const int row = blockIdx.x;          // token index 0..8191
    const int t   = tok[row];
    float4 v = ((const float4*)(emb + (long long)t * 1024))[threadIdx.x];
    ((float4*)(x + (long long)row * 1024))[threadIdx.x] = v;
    uint2 p;
    p.x = (u32)f2bf(v.x) | ((u32)f2bf(v.y) << 16);
    p.y = (u32)f2bf(v.z) | ((u32)f2bf(v.w) << 16);
    ((uint2*)(xb + (long long)row * 1024))[threadIdx.x] = p;
}

__global__ void pack_bias(const float* __restrict__ bq, const float* __restrict__ bk,
                          const float* __restrict__ bv, float* __restrict__ out)
{
    int i = blockIdx.x * 256 + threadIdx.x;   // L*3072 total
    int l = i / 3072, j = i % 3072;
    float v = (j < 1024) ? bq[l * 1024 + j]
            : (j < 2048) ? bk[l * 1024 + j - 1024]
                         : bv[l * 1024 + j - 2048];
    out[i] = v;
}

// ---------------------------------------------------------------------------
extern "C" void kernel_launch(void* const* d_in, const int* in_sizes, int n_in,
                              void* d_out, int out_size, void* d_ws, size_t ws_size,
                              hipStream_t stream)
{
    const int*   tok  = (const int*)d_in[0];
    const float* emb  = (const float*)d_in[1];
    const float* Wq   = (const float*)d_in[2];
    const float* bq   = (const float*)d_in[3];
    const float* Wk   = (const float*)d_in[4];
    const float* bk   = (const float*)d_in[5];
    const float* Wv   = (const float*)d_in[6];
    const float* bv   = (const float*)d_in[7];
    const float* Wm   = (const float*)d_in[8];
    const float* bm   = (const float*)d_in[9];
    const float* Wout = (const float*)d_in[10];
    const float* bout = (const float*)d_in[11];
    float* out = (float*)d_out;

    constexpr int B = 8, S = 1024, H = 1024, V = 512, L = 6;
    constexpr long long M = (long long)B * S;  // 8192

    char* ws = (char*)d_ws;
    u16*   WqkvT = (u16*)ws;   ws += (long long)L * 3 * H * H * 2;  // [L][3H][H]
    u16*   WmT   = (u16*)ws;   ws += (long long)L * H * H * 2;      // [L][H][H]
    u16*   WoutT = (u16*)ws;   ws += (long long)V * H * 2;          // [V][H]
    float* bqkv  = (float*)ws; ws += (long long)L * 3 * H * 4;      // [L][3H]
    float* x     = (float*)ws; ws += M * H * 4;                     // residual f32
    u16*   xb    = (u16*)ws;   ws += M * H * 2;                     // residual bf16
    u16*   QKV   = (u16*)ws;   ws += M * 3 * H * 2;                 // [M][3H]
    u16*   attnT = (u16*)ws;   ws += (long long)B * S * S * 2;      // [b][q][k]
    u16*   Vt    = (u16*)ws;   ws += (long long)B * S * S * 2;      // [b][h][s]
    u16*   ctxb  = (u16*)ws;   ws += M * H * 2;                     // [M][H]

    float* attnOut = out + (long long)B * S * V;  // [L][B][S(key)][S(query)]

    const dim3 tb(64, 4);
    // weight transposes (f32 -> bf16, [K][N] -> [N][K])
    transpose_bf16<float><<<dim3(16, 16, L), tb, 0, stream>>>(
        Wq, H, (long long)H * H, WqkvT, H, (long long)3 * H * H);
    transpose_bf16<float><<<dim3(16, 16, L), tb, 0, stream>>>(
        Wk, H, (long long)H * H, WqkvT + (long long)H * H, H, (long long)3 * H * H);
    transpose_bf16<float><<<dim3(16, 16, L), tb, 0, stream>>>(
        Wv, H, (long long)H * H, WqkvT + (long long)2 * H * H, H, (long long)3 * H * H);
    transpose_bf16<float><<<dim3(16, 16, L), tb, 0, stream>>>(
        Wm, H, (long long)H * H, WmT, H, (long long)H * H);
    transpose_bf16<float><<<dim3(V / 64, 16, 1), tb, 0, stream>>>(
        Wout, V, 0, WoutT, H, 0);
    pack_bias<<<(L * 3 * H) / 256, 256, 0, stream>>>(bq, bk, bv, bqkv);
    embed_kernel<<<M, 256, 0, stream>>>(tok, emb, x, xb);

    for (int l = 0; l < L; ++l) {
        // QKV = xb @ [Wq|Wk|Wv] + bias  -> bf16 [M][3H]
        gemm_bt<EPI_QKV><<<dim3(3 * H / 128, M / 128, 1), 256, 0, stream>>>(
            xb, H, 0, WqkvT + (long long)l * 3 * H * H, H, 0,
            QKV, 3 * H, 0, H, bqkv + l * 3 * H, nullptr, nullptr, nullptr, 0.f);

        // logits[k,q] = K . Q * scale + causal mask  -> f32, in-place in d_out
        float* attnL = attnOut + (long long)l * B * S * S;
        gemm_bt<EPI_LOGITS><<<dim3(S / 128, S / 128, B), 256, 0, stream>>>(
            QKV + H, 3 * H, (long long)S * 3 * H,
            QKV, 3 * H, (long long)S * 3 * H,
            attnL, S, (long long)S * S, H,
            nullptr, nullptr, nullptr, nullptr, 0.03125f);

        softmax_cols<<<dim3(S / 64, B), dim3(64, 16), 0, stream>>>(attnL, (long long)S * S);

        // attn [k,q] f32 -> attnT [q,k] bf16 ; V [s,h] -> Vt [h,s] bf16
        transpose_bf16<float><<<dim3(16, 16, B), tb, 0, stream>>>(
            attnL, S, (long long)S * S, attnT, S, (long long)S * S);
        transpose_bf16<u16><<<dim3(16, 16, B), tb, 0, stream>>>(
            QKV + 2 * H, 3 * H, (long long)S * 3 * H, Vt, S, (long long)S * S);

        // ctx[q,h] = sum_k attnT[q,k] * Vt[h,k]  -> bf16 [M][H]
        gemm_bt<EPI_CTX><<<dim3(H / 128, S / 128, B), 256, 0, stream>>>(
            attnT, S, (long long)S * S, Vt, S, (long long)S * S,
            ctxb, H, (long long)S * H, S,
            nullptr, nullptr, nullptr, nullptr, 0.f);

        // x = x + ctx + relu(ctx @ Wm + bm); xb = bf16(x)
        gemm_bt<EPI_MLP><<<dim3(H / 128, M / 128, 1), 256, 0, stream>>>(
            ctxb, H, 0, WmT + (long long)l * H * H, H, 0,
            nullptr, H, 0, H, bm + l * H, x, ctxb, xb, 0.f);
    }

    // out = xb @ Wout + bout  -> f32
    gemm_bt<EPI_OUT><<<dim3(V / 128, M / 128, 1), 256, 0, stream>>>(
        xb, H, 0, WoutT, H, 0, out, V, 0, H,
        bout, nullptr, nullptr, nullptr, 0.f);
}

// Round 2
// 1542.773 us; speedup vs baseline: 1.1926x; 1.1926x over previous
//
#include <hip/hip_runtime.h>
#include <stdint.h>

typedef unsigned short u16;
typedef unsigned int u32;
typedef __bf16 bf16x8 __attribute__((ext_vector_type(8)));
typedef float floatx4 __attribute__((ext_vector_type(4)));

#define NEG_INF_F (-10000000.0f)

__device__ __forceinline__ float bf2f(u16 u) {
    union { u32 u; float f; } x; x.u = ((u32)u) << 16; return x.f;
}
__device__ __forceinline__ u16 f2bf(float f) {
    union { float f; u32 u; } x; x.f = f;
    u32 r = x.u + 0x7fffu + ((x.u >> 16) & 1u);   // RNE
    return (u16)(r >> 16);
}

__device__ __forceinline__ void async_cp16(const void* g, void* l) {
    __builtin_amdgcn_global_load_lds(
        (const __attribute__((address_space(1))) void*)g,
        (__attribute__((address_space(3))) void*)l, 16, 0, 0);
}

// ---------------------------------------------------------------------------
// BT GEMM: C[m,n] = sum_k A[m,k] * B[n,k]
// 128x128 tile, 256 threads (4 waves 2x2), mfma_f32_16x16x32_bf16, BK=64,
// global_load_lds width-16 staging with 16B-group XOR swizzle:
//   element (r,k) stored at LDS linear r*64 + ((k>>3) ^ (r&7))*8 + (k&7)
// Staging absorbs the XOR into the *global* source address (LDS dst must be
// wave-uniform base + lane*16). Fragment ds_read_b128 becomes <=2-way banked.
// ---------------------------------------------------------------------------
enum { EPI_QKV = 0, EPI_LOGITS = 1, EPI_CTX = 2, EPI_MLP = 3, EPI_OUT = 4 };

template <int EPI>
__global__ __launch_bounds__(256) void gemm_bt(
    const u16* __restrict__ A, int lda, long long aBatch,
    const u16* __restrict__ B, int ldb, long long bBatch,
    void* __restrict__ Cv, int ldc, long long cBatch,
    int K,
    const float* __restrict__ bias,
    float* __restrict__ xbuf,          // EPI_MLP: residual stream (read+write)
    const u16* __restrict__ ctxb,      // EPI_MLP: ctx bf16 (read)
    u16* __restrict__ xb,              // EPI_MLP: bf16 copy of new x (write)
    float scale)
{
    __shared__ __align__(16) u16 sA[128 * 64];   // 16 KB
    __shared__ __align__(16) u16 sB[128 * 64];   // 16 KB

    const int tid  = threadIdx.x;
    const int wave = tid >> 6;
    const int lane = tid & 63;
    const int bz   = blockIdx.z;

    const u16* Ab = A + (long long)bz * aBatch + (long long)(blockIdx.y * 128) * lda;
    const u16* Bb = B + (long long)bz * bBatch + (long long)(blockIdx.x * 128) * ldb;

    const int wm = wave >> 1, wn = wave & 1;
    const int quad = lane >> 4;

    // staging: 16 calls/matrix, call c covers rows c*8..c*8+7 (8 lanes/row).
    // lane -> row offset (lane>>3), stored group gs=(lane&7); fetch the
    // swizzled source group gf = gs ^ (row&7) = (lane&7) ^ ((lane>>3)&7).
    const int srowoff = lane >> 3;
    const int gf      = (lane & 7) ^ ((lane >> 3) & 7);

    // fragment read: row r = 64*w? + (lane&15) + 16*mi; r&7 == lane&7 for all mi
    const int ra = 64 * wm + (lane & 15);
    const int rb = 64 * wn + (lane & 15);
    const int rx7 = lane & 7;

    floatx4 zero = {0.f, 0.f, 0.f, 0.f};
    floatx4 acc[4][4];
#pragma unroll
    for (int i = 0; i < 4; ++i)
#pragma unroll
        for (int j = 0; j < 4; ++j) acc[i][j] = zero;

    for (int k0 = 0; k0 < K; k0 += 64) {
#pragma unroll
        for (int i = 0; i < 4; ++i) {
            const int c = wave * 4 + i;
            const int r = c * 8 + srowoff;
            async_cp16(Ab + (long long)r * lda + k0 + gf * 8, &sA[c * 512 + lane * 8]);
            async_cp16(Bb + (long long)r * ldb + k0 + gf * 8, &sB[c * 512 + lane * 8]);
        }
        __syncthreads();

#pragma unroll
        for (int kk = 0; kk < 64; kk += 32) {
            const int gbase = kk >> 3;                       // k-group of this sub-block
            const int ga = ((gbase + quad) ^ rx7) << 3;      // swizzled element group
            bf16x8 af[4], bf[4];
#pragma unroll
            for (int mi = 0; mi < 4; ++mi)
                af[mi] = *(const bf16x8*)&sA[(ra + 16 * mi) * 64 + ga];
#pragma unroll
            for (int ni = 0; ni < 4; ++ni)
                bf[ni] = *(const bf16x8*)&sB[(rb + 16 * ni) * 64 + ga];
#pragma unroll
            for (int mi = 0; mi < 4; ++mi)
#pragma unroll
                for (int ni = 0; ni < 4; ++ni)
                    acc[mi][ni] = __builtin_amdgcn_mfma_f32_16x16x32_bf16(
                        af[mi], bf[ni], acc[mi][ni], 0, 0, 0);
        }
        __syncthreads();
    }

    // epilogue: C/D layout col = lane&15, row = (lane>>4)*4 + reg  [m89-verified]
    const int m0 = blockIdx.y * 128 + 64 * wm + (quad << 2);
    const int n0 = blockIdx.x * 128 + 64 * wn + (lane & 15);
#pragma unroll
    for (int mi = 0; mi < 4; ++mi) {
#pragma unroll
        for (int ni = 0; ni < 4; ++ni) {
            const int gn = n0 + ni * 16;
#pragma unroll
            for (int r = 0; r < 4; ++r) {
                const int gm = m0 + mi * 16 + r;
                float v = acc[mi][ni][r];
                if constexpr (EPI == EPI_QKV) {
                    v += bias[gn];
                    ((u16*)Cv)[(long long)bz * cBatch + (long long)gm * ldc + gn] = f2bf(v);
                } else if constexpr (EPI == EPI_LOGITS) {
                    v = v * scale + (gm > gn ? NEG_INF_F : 0.0f);  // m=key, n=query
                    ((float*)Cv)[(long long)bz * cBatch + (long long)gm * ldc + gn] = v;
                } else if constexpr (EPI == EPI_CTX) {
                    ((u16*)Cv)[(long long)bz * cBatch + (long long)gm * ldc + gn] = f2bf(v);
                } else if constexpr (EPI == EPI_MLP) {
                    const long long idx = (long long)gm * ldc + gn;
                    v += bias[gn];
                    v = fmaxf(v, 0.0f);
                    float xv = xbuf[idx] + bf2f(ctxb[idx]) + v;  // x + ctx + relu(mlp)
                    xbuf[idx] = xv;
                    xb[idx]   = f2bf(xv);
                } else {  // EPI_OUT
                    v += bias[gn];
                    ((float*)Cv)[(long long)gm * ldc + gn] = v;
                }
            }
        }
    }
}

// ---------------------------------------------------------------------------
// Tiled transpose -> bf16 (used for weights and V). in: R x C row-major.
// Grid: (C/64, R/64, batches), block (64,4).
// ---------------------------------------------------------------------------
template <typename Tin>
__global__ void transpose_bf16(const Tin* __restrict__ in, int inStride, long long inBatch,
                               u16* __restrict__ out, int outStride, long long outBatch)
{
    __shared__ float tile[64][65];
    const Tin* ib = in + (long long)blockIdx.z * inBatch;
    u16* ob       = out + (long long)blockIdx.z * outBatch;
    const int r0 = blockIdx.y * 64, c0 = blockIdx.x * 64;
    const int x = threadIdx.x, y = threadIdx.y;
#pragma unroll
    for (int j = 0; j < 16; ++j) {
        int r = y + j * 4;
        float v;
        if constexpr (sizeof(Tin) == 2)
            v = bf2f(((const u16*)ib)[(long long)(r0 + r) * inStride + c0 + x]);
        else
            v = ((const float*)ib)[(long long)(r0 + r) * inStride + c0 + x];
        tile[r][x] = v;
    }
    __syncthreads();
#pragma unroll
    for (int j = 0; j < 16; ++j) {
        int r = y + j * 4;
        ob[(long long)(c0 + r) * outStride + r0 + x] = f2bf(tile[x][r]);
    }
}

// ---------------------------------------------------------------------------
// Fused column-softmax (over key axis) + transposed bf16 emission.
// In-place normalize attn[k][q] (f32) and write attnT[q][k] (bf16).
// Grid (S/16, B), block (16,64): thread (x,ky) owns column q = blk*16+x,
// contiguous k-chunk [ky*16, ky*16+16) held in registers (one global read).
// ---------------------------------------------------------------------------
__global__ __launch_bounds__(1024) void softmax_emit(
    float* __restrict__ attn, long long batchStride,
    u16* __restrict__ attnT, long long tBatchStride)
{
    __shared__ float sm[64][16], sl[64][16], sm2[8][16], sl2[8][16];
    __shared__ float sM[16], sInv[16];

    float* base = attn + (long long)blockIdx.y * batchStride;
    const int x = threadIdx.x, ky = threadIdx.y;
    const int q = blockIdx.x * 16 + x;

    float v[16];
    float m = -3.4e38f, l = 0.f;
#pragma unroll
    for (int j = 0; j < 16; ++j) {
        v[j] = base[(long long)(ky * 16 + j) * 1024 + q];
        float mn = fmaxf(m, v[j]);
        l = l * __expf(m - mn) + __expf(v[j] - mn);
        m = mn;
    }
    sm[ky][x] = m;
    sl[ky][x] = l;
    __syncthreads();
    if (ky < 8) {
        float M = -3.4e38f, L = 0.f;
#pragma unroll
        for (int t = 0; t < 8; ++t) {
            float mm = sm[ky + 8 * t][x], ll = sl[ky + 8 * t][x];
            float mn = fmaxf(M, mm);
            L = L * __expf(M - mn) + ll * __expf(mm - mn);
            M = mn;
        }
        sm2[ky][x] = M;
        sl2[ky][x] = L;
    }
    __syncthreads();
    if (ky == 0) {
        float M = -3.4e38f, L = 0.f;
#pragma unroll
        for (int t = 0; t < 8; ++t) {
            float mm = sm2[t][x], ll = sl2[t][x];
            float mn = fmaxf(M, mm);
            L = L * __expf(M - mn) + ll * __expf(mm - mn);
            M = mn;
        }
        sM[x]   = M;
        sInv[x] = 1.0f / L;
    }
    __syncthreads();
    const float M = sM[x], inv = sInv[x];

    u16 pb[16];
#pragma unroll
    for (int j = 0; j < 16; ++j) {
        float p = __expf(v[j] - M) * inv;
        base[(long long)(ky * 16 + j) * 1024 + q] = p;
        pb[j] = f2bf(p);
    }
    // attnT[q][ky*16 .. +15]: 32 B contiguous per thread
    u16* trow = attnT + (long long)blockIdx.y * tBatchStride + (long long)q * 1024 + ky * 16;
    ((uint4*)trow)[0] = *(const uint4*)&pb[0];
    ((uint4*)trow)[1] = *(const uint4*)&pb[8];
}

// ---------------------------------------------------------------------------
__global__ void embed_kernel(const int* __restrict__ tok, const float* __restrict__ emb,
                             float* __restrict__ x, u16* __restrict__ xb)
{
    const int row = blockIdx.x;          // token index 0..8191
    const int t   = tok[row];
    float4 v = ((const float4*)(emb + (long long)t * 1024))[threadIdx.x];
    ((float4*)(x + (long long)row * 1024))[threadIdx.x] = v;
    uint2 p;
    p.x = (u32)f2bf(v.x) | ((u32)f2bf(v.y) << 16);
    p.y = (u32)f2bf(v.z) | ((u32)f2bf(v.w) << 16);
    ((uint2*)(xb + (long long)row * 1024))[threadIdx.x] = p;
}

__global__ void pack_bias(const float* __restrict__ bq, const float* __restrict__ bk,
                          const float* __restrict__ bv, float* __restrict__ out)
{
    int i = blockIdx.x * 256 + threadIdx.x;   // L*3072 total
    int l = i / 3072, j = i % 3072;
    float v = (j < 1024) ? bq[l * 1024 + j]
            : (j < 2048) ? bk[l * 1024 + j - 1024]
                         : bv[l * 1024 + j - 2048];
    out[i] = v;
}

// ---------------------------------------------------------------------------
extern "C" void kernel_launch(void* const* d_in, const int* in_sizes, int n_in,
                              void* d_out, int out_size, void* d_ws, size_t ws_size,
                              hipStream_t stream)
{
    const int*   tok  = (const int*)d_in[0];
    const float* emb  = (const float*)d_in[1];
    const float* Wq   = (const float*)d_in[2];
    const float* bq   = (const float*)d_in[3];
    const float* Wk   = (const float*)d_in[4];
    const float* bk   = (const float*)d_in[5];
    const float* Wv   = (const float*)d_in[6];
    const float* bv   = (const float*)d_in[7];
    const float* Wm   = (const float*)d_in[8];
    const float* bm   = (const float*)d_in[9];
    const float* Wout = (const float*)d_in[10];
    const float* bout = (const float*)d_in[11];
    float* out = (float*)d_out;

    constexpr int B = 8, S = 1024, H = 1024, V = 512, L = 6;
    constexpr long long M = (long long)B * S;  // 8192

    char* ws = (char*)d_ws;
    u16*   WqkvT = (u16*)ws;   ws += (long long)L * 3 * H * H * 2;  // [L][3H][H]
    u16*   WmT   = (u16*)ws;   ws += (long long)L * H * H * 2;      // [L][H][H]
    u16*   WoutT = (u16*)ws;   ws += (long long)V * H * 2;          // [V][H]
    float* bqkv  = (float*)ws; ws += (long long)L * 3 * H * 4;      // [L][3H]
    float* x     = (float*)ws; ws += M * H * 4;                     // residual f32
    u16*   xb    = (u16*)ws;   ws += M * H * 2;                     // residual bf16
    u16*   QKV   = (u16*)ws;   ws += M * 3 * H * 2;                 // [M][3H]
    u16*   attnT = (u16*)ws;   ws += (long long)B * S * S * 2;      // [b][q][k]
    u16*   Vt    = (u16*)ws;   ws += (long long)B * S * S * 2;      // [b][h][s]
    u16*   ctxb  = (u16*)ws;   ws += M * H * 2;                     // [M][H]

    float* attnOut = out + (long long)B * S * V;  // [L][B][S(key)][S(query)]

    const dim3 tb(64, 4);
    // weight transposes (f32 -> bf16, [K][N] -> [N][K])
    transpose_bf16<float><<<dim3(16, 16, L), tb, 0, stream>>>(
        Wq, H, (long long)H * H, WqkvT, H, (long long)3 * H * H);
    transpose_bf16<float><<<dim3(16, 16, L), tb, 0, stream>>>(
        Wk, H, (long long)H * H, WqkvT + (long long)H * H, H, (long long)3 * H * H);
    transpose_bf16<float><<<dim3(16, 16, L), tb, 0, stream>>>(
        Wv, H, (long long)H * H, WqkvT + (long long)2 * H * H, H, (long long)3 * H * H);
    transpose_bf16<float><<<dim3(16, 16, L), tb, 0, stream>>>(
        Wm, H, (long long)H * H, WmT, H, (long long)H * H);
    transpose_bf16<float><<<dim3(V / 64, 16, 1), tb, 0, stream>>>(
        Wout, V, 0, WoutT, H, 0);
    pack_bias<<<(L * 3 * H) / 256, 256, 0, stream>>>(bq, bk, bv, bqkv);
    embed_kernel<<<M, 256, 0, stream>>>(tok, emb, x, xb);

    for (int l = 0; l < L; ++l) {
        // QKV = xb @ [Wq|Wk|Wv] + bias  -> bf16 [M][3H]
        gemm_bt<EPI_QKV><<<dim3(3 * H / 128, M / 128, 1), 256, 0, stream>>>(
            xb, H, 0, WqkvT + (long long)l * 3 * H * H, H, 0,
            QKV, 3 * H, 0, H, bqkv + l * 3 * H, nullptr, nullptr, nullptr, 0.f);

        // logits[k,q] = K . Q * scale + causal mask  -> f32, in-place in d_out
        float* attnL = attnOut + (long long)l * B * S * S;
        gemm_bt<EPI_LOGITS><<<dim3(S / 128, S / 128, B), 256, 0, stream>>>(
            QKV + H, 3 * H, (long long)S * 3 * H,
            QKV, 3 * H, (long long)S * 3 * H,
            attnL, S, (long long)S * S, H,
            nullptr, nullptr, nullptr, nullptr, 0.03125f);

        // softmax over k + emit attnT bf16 [b][q][k]
        softmax_emit<<<dim3(S / 16, B), dim3(16, 64), 0, stream>>>(
            attnL, (long long)S * S, attnT, (long long)S * S);

        // V [s,h] -> Vt [h,s] bf16
        transpose_bf16<u16><<<dim3(16, 16, B), tb, 0, stream>>>(
            QKV + 2 * H, 3 * H, (long long)S * 3 * H, Vt, S, (long long)S * S);

        // ctx[q,h] = sum_k attnT[q,k] * Vt[h,k]  -> bf16 [M][H]
        gemm_bt<EPI_CTX><<<dim3(H / 128, S / 128, B), 256, 0, stream>>>(
            attnT, S, (long long)S * S, Vt, S, (long long)S * S,
            ctxb, H, (long long)S * H, S,
            nullptr, nullptr, nullptr, nullptr, 0.f);

        // x = x + ctx + relu(ctx @ Wm + bm); xb = bf16(x)
        gemm_bt<EPI_MLP><<<dim3(H / 128, M / 128, 1), 256, 0, stream>>>(
            ctxb, H, 0, WmT + (long long)l * H * H, H, 0,
            nullptr, H, 0, H, bm + l * H, x, ctxb, xb, 0.f);
    }

    // out = xb @ Wout + bout  -> f32
    gemm_bt<EPI_OUT><<<dim3(V / 128, M / 128, 1), 256, 0, stream>>>(
        xb, H, 0, WoutT, H, 0, out, V, 0, H,
        bout, nullptr, nullptr, nullptr, 0.f);
}

// Round 3
// 1490.020 us; speedup vs baseline: 1.2348x; 1.0354x over previous
//
#include <hip/hip_runtime.h>
#include <stdint.h>

typedef unsigned short u16;
typedef unsigned int u32;
typedef __bf16 bf16x8 __attribute__((ext_vector_type(8)));
typedef float floatx4 __attribute__((ext_vector_type(4)));

#define NEG_INF_F (-10000000.0f)

__device__ __forceinline__ float bf2f(u16 u) {
    union { u32 u; float f; } x; x.u = ((u32)u) << 16; return x.f;
}
__device__ __forceinline__ u16 f2bf(float f) {
    union { float f; u32 u; } x; x.f = f;
    u32 r = x.u + 0x7fffu + ((x.u >> 16) & 1u);   // RNE
    return (u16)(r >> 16);
}

__device__ __forceinline__ void async_cp16(const void* g, void* l) {
    __builtin_amdgcn_global_load_lds(
        (const __attribute__((address_space(1))) void*)g,
        (__attribute__((address_space(3))) void*)l, 16, 0, 0);
}

// ---------------------------------------------------------------------------
// BT GEMM: C[m,n] = sum_k A[m,k] * B[n,k]
// 128x128 tile, 256 threads (4 waves 2x2), mfma_f32_16x16x32_bf16, BK=64,
// global_load_lds width-16 staging with 16B-group XOR swizzle:
//   element (r,k) stored at LDS linear r*64 + ((k>>3) ^ (r&7))*8 + (k&7)
// EPI_LOGITS: 1D lower-triangle grid (only k-tile <= q-tile computed).
// EPI_CTX:    K-loop truncated to min(K, (q_tile+1)*128) (causal zeros).
// ---------------------------------------------------------------------------
enum { EPI_QKV = 0, EPI_LOGITS = 1, EPI_CTX = 2, EPI_MLP = 3, EPI_OUT = 4 };

template <int EPI>
__global__ __launch_bounds__(256) void gemm_bt(
    const u16* __restrict__ A, int lda, long long aBatch,
    const u16* __restrict__ B, int ldb, long long bBatch,
    void* __restrict__ Cv, int ldc, long long cBatch,
    int K,
    const float* __restrict__ bias,
    float* __restrict__ xbuf,          // EPI_MLP: residual stream (read+write)
    const u16* __restrict__ ctxb,      // EPI_MLP: ctx bf16 (read)
    u16* __restrict__ xb,              // EPI_MLP: bf16 copy of new x (write)
    float scale)
{
    __shared__ __align__(16) u16 sA[128 * 64];   // 16 KB
    __shared__ __align__(16) u16 sB[128 * 64];   // 16 KB

    const int tid  = threadIdx.x;
    const int wave = tid >> 6;
    const int lane = tid & 63;
    const int bz   = blockIdx.z;

    int bxE = blockIdx.x, byE = blockIdx.y;
    if constexpr (EPI == EPI_LOGITS) {
        // triangular decode: blockIdx.x = t -> (tq >= tk)
        const int t = blockIdx.x;
        int tq = (int)((sqrtf(8.0f * t + 1.0f) - 1.0f) * 0.5f);
        while ((tq + 1) * (tq + 2) / 2 <= t) ++tq;
        while (tq * (tq + 1) / 2 > t) --tq;
        bxE = tq;                       // n-tile = query
        byE = t - tq * (tq + 1) / 2;    // m-tile = key  (<= tq)
    }
    int Keff = K;
    if constexpr (EPI == EPI_CTX) Keff = min(K, (byE + 1) * 128);

    const u16* Ab = A + (long long)bz * aBatch + (long long)(byE * 128) * lda;
    const u16* Bb = B + (long long)bz * bBatch + (long long)(bxE * 128) * ldb;

    const int wm = wave >> 1, wn = wave & 1;
    const int quad = lane >> 4;

    // staging: 16 calls/matrix, call c covers rows c*8..c*8+7 (8 lanes/row).
    const int srowoff = lane >> 3;
    const int gf      = (lane & 7) ^ ((lane >> 3) & 7);

    const int ra = 64 * wm + (lane & 15);
    const int rb = 64 * wn + (lane & 15);
    const int rx7 = lane & 7;

    floatx4 zero = {0.f, 0.f, 0.f, 0.f};
    floatx4 acc[4][4];
#pragma unroll
    for (int i = 0; i < 4; ++i)
#pragma unroll
        for (int j = 0; j < 4; ++j) acc[i][j] = zero;

    for (int k0 = 0; k0 < Keff; k0 += 64) {
#pragma unroll
        for (int i = 0; i < 4; ++i) {
            const int c = wave * 4 + i;
            const int r = c * 8 + srowoff;
            async_cp16(Ab + (long long)r * lda + k0 + gf * 8, &sA[c * 512 + lane * 8]);
            async_cp16(Bb + (long long)r * ldb + k0 + gf * 8, &sB[c * 512 + lane * 8]);
        }
        __syncthreads();

#pragma unroll
        for (int kk = 0; kk < 64; kk += 32) {
            const int gbase = kk >> 3;
            const int ga = ((gbase + quad) ^ rx7) << 3;
            bf16x8 af[4], bf[4];
#pragma unroll
            for (int mi = 0; mi < 4; ++mi)
                af[mi] = *(const bf16x8*)&sA[(ra + 16 * mi) * 64 + ga];
#pragma unroll
            for (int ni = 0; ni < 4; ++ni)
                bf[ni] = *(const bf16x8*)&sB[(rb + 16 * ni) * 64 + ga];
#pragma unroll
            for (int mi = 0; mi < 4; ++mi)
#pragma unroll
                for (int ni = 0; ni < 4; ++ni)
                    acc[mi][ni] = __builtin_amdgcn_mfma_f32_16x16x32_bf16(
                        af[mi], bf[ni], acc[mi][ni], 0, 0, 0);
        }
        __syncthreads();
    }

    // epilogue: C/D layout col = lane&15, row = (lane>>4)*4 + reg  [m89-verified]
    const int m0 = byE * 128 + 64 * wm + (quad << 2);
    const int n0 = bxE * 128 + 64 * wn + (lane & 15);
#pragma unroll
    for (int mi = 0; mi < 4; ++mi) {
#pragma unroll
        for (int ni = 0; ni < 4; ++ni) {
            const int gn = n0 + ni * 16;
#pragma unroll
            for (int r = 0; r < 4; ++r) {
                const int gm = m0 + mi * 16 + r;
                float v = acc[mi][ni][r];
                if constexpr (EPI == EPI_QKV) {
                    v += bias[gn];
                    ((u16*)Cv)[(long long)bz * cBatch + (long long)gm * ldc + gn] = f2bf(v);
                } else if constexpr (EPI == EPI_LOGITS) {
                    v = v * scale + (gm > gn ? NEG_INF_F : 0.0f);  // m=key, n=query
                    ((float*)Cv)[(long long)bz * cBatch + (long long)gm * ldc + gn] = v;
                } else if constexpr (EPI == EPI_CTX) {
                    ((u16*)Cv)[(long long)bz * cBatch + (long long)gm * ldc + gn] = f2bf(v);
                } else if constexpr (EPI == EPI_MLP) {
                    const long long idx = (long long)gm * ldc + gn;
                    v += bias[gn];
                    v = fmaxf(v, 0.0f);
                    float xv = xbuf[idx] + bf2f(ctxb[idx]) + v;  // x + ctx + relu(mlp)
                    xbuf[idx] = xv;
                    xb[idx]   = f2bf(xv);
                } else {  // EPI_OUT
                    v += bias[gn];
                    ((float*)Cv)[(long long)gm * ldc + gn] = v;
                }
            }
        }
    }
}

// ---------------------------------------------------------------------------
// Tiled transpose -> bf16 (V per layer). in: R x C row-major.
// Grid: (C/64, R/64, batches), block (64,4).
// ---------------------------------------------------------------------------
template <typename Tin>
__global__ void transpose_bf16(const Tin* __restrict__ in, int inStride, long long inBatch,
                               u16* __restrict__ out, int outStride, long long outBatch)
{
    __shared__ float tile[64][65];
    const Tin* ib = in + (long long)blockIdx.z * inBatch;
    u16* ob       = out + (long long)blockIdx.z * outBatch;
    const int r0 = blockIdx.y * 64, c0 = blockIdx.x * 64;
    const int x = threadIdx.x, y = threadIdx.y;
#pragma unroll
    for (int j = 0; j < 16; ++j) {
        int r = y + j * 4;
        float v;
        if constexpr (sizeof(Tin) == 2)
            v = bf2f(((const u16*)ib)[(long long)(r0 + r) * inStride + c0 + x]);
        else
            v = ((const float*)ib)[(long long)(r0 + r) * inStride + c0 + x];
        tile[r][x] = v;
    }
    __syncthreads();
#pragma unroll
    for (int j = 0; j < 16; ++j) {
        int r = y + j * 4;
        ob[(long long)(c0 + r) * outStride + r0 + x] = f2bf(tile[x][r]);
    }
}

// ---------------------------------------------------------------------------
// Setup mega-kernel: all weight transposes (f32->bf16) + bias packing in one
// launch. Block (64,4). Grid (16,16, 4L+2):
//   z in [0,   L): Wq  -> WqkvT[l][0H..]
//   z in [L,  2L): Wk  -> WqkvT[l][1H..]
//   z in [2L, 3L): Wv  -> WqkvT[l][2H..]
//   z in [3L, 4L): Wm  -> WmT[l]
//   z == 4L      : Wout [H][V] -> WoutT [V][H]   (blocks x>=V/64 idle)
//   z == 4L+1    : pack bqkv                     (flat threads)
// ---------------------------------------------------------------------------
template <int L, int H, int V>
__global__ void setup_weights(const float* __restrict__ Wq, const float* __restrict__ Wk,
                              const float* __restrict__ Wv, const float* __restrict__ Wm,
                              const float* __restrict__ Wout,
                              const float* __restrict__ bq, const float* __restrict__ bk,
                              const float* __restrict__ bv,
                              u16* __restrict__ WqkvT, u16* __restrict__ WmT,
                              u16* __restrict__ WoutT, float* __restrict__ bqkv)
{
    const int z = blockIdx.z;
    if (z == 4 * L + 1) {
        int i = ((blockIdx.y * 16 + blockIdx.x) * 256) + threadIdx.y * 64 + threadIdx.x;
        if (i < L * 3 * H) {
            int l = i / (3 * H), j = i % (3 * H);
            float v = (j < H) ? bq[l * H + j]
                    : (j < 2 * H) ? bk[l * H + j - H]
                                  : bv[l * H + j - 2 * H];
            bqkv[i] = v;
        }
        return;
    }

    const float* in;
    u16* outp;
    int inStride, outStride;
    if (z == 4 * L) {
        if (blockIdx.x >= V / 64) return;
        in = Wout; inStride = V;
        outp = WoutT; outStride = H;
    } else {
        const int which = z / L, l = z % L;
        inStride = H; outStride = H;
        if (which == 3) { in = Wm + (long long)l * H * H; outp = WmT + (long long)l * H * H; }
        else {
            in   = (which == 0 ? Wq : which == 1 ? Wk : Wv) + (long long)l * H * H;
            outp = WqkvT + (long long)l * 3 * H * H + (long long)which * H * H;
        }
    }

    __shared__ float tile[64][65];
    const int r0 = blockIdx.y * 64, c0 = blockIdx.x * 64;
    const int x = threadIdx.x, y = threadIdx.y;
#pragma unroll
    for (int j = 0; j < 16; ++j) {
        int r = y + j * 4;
        tile[r][x] = in[(long long)(r0 + r) * inStride + c0 + x];
    }
    __syncthreads();
#pragma unroll
    for (int j = 0; j < 16; ++j) {
        int r = y + j * 4;
        outp[(long long)(c0 + r) * outStride + r0 + x] = f2bf(tile[x][r]);
    }
}

// ---------------------------------------------------------------------------
// Fused causal column-softmax (over key axis) + transposed bf16 emission.
// Masked entries (k > q) are never read (their logits tiles were skipped);
// they produce exact 0.0 f32 and 0 bf16, matching reference underflow.
// Grid (S/16, B), block (16,64).
// ---------------------------------------------------------------------------
__global__ __launch_bounds__(1024) void softmax_emit(
    float* __restrict__ attn, long long batchStride,
    u16* __restrict__ attnT, long long tBatchStride)
{
    __shared__ float sm[64][16], sl[64][16], sm2[8][16], sl2[8][16];
    __shared__ float sM[16], sInv[16];

    float* base = attn + (long long)blockIdx.y * batchStride;
    const int x = threadIdx.x, ky = threadIdx.y;
    const int q = blockIdx.x * 16 + x;

    float v[16];
    float m = -3.4e38f, l = 0.f;
#pragma unroll
    for (int j = 0; j < 16; ++j) {
        const int k = ky * 16 + j;
        float vj = NEG_INF_F;
        if (k <= q) vj = base[(long long)k * 1024 + q];
        v[j] = vj;
        float mn = fmaxf(m, vj);
        l = l * __expf(m - mn) + __expf(vj - mn);
        m = mn;
    }
    sm[ky][x] = m;
    sl[ky][x] = l;
    __syncthreads();
    if (ky < 8) {
        float M = -3.4e38f, L = 0.f;
#pragma unroll
        for (int t = 0; t < 8; ++t) {
            float mm = sm[ky + 8 * t][x], ll = sl[ky + 8 * t][x];
            float mn = fmaxf(M, mm);
            L = L * __expf(M - mn) + ll * __expf(mm - mn);
            M = mn;
        }
        sm2[ky][x] = M;
        sl2[ky][x] = L;
    }
    __syncthreads();
    if (ky == 0) {
        float M = -3.4e38f, L = 0.f;
#pragma unroll
        for (int t = 0; t < 8; ++t) {
            float mm = sm2[t][x], ll = sl2[t][x];
            float mn = fmaxf(M, mm);
            L = L * __expf(M - mn) + ll * __expf(mm - mn);
            M = mn;
        }
        sM[x]   = M;
        sInv[x] = 1.0f / L;
    }
    __syncthreads();
    const float M = sM[x], inv = sInv[x];

    u16 pb[16];
#pragma unroll
    for (int j = 0; j < 16; ++j) {
        float p = __expf(v[j] - M) * inv;   // masked: exp(-1e7 - M) underflows to 0
        base[(long long)(ky * 16 + j) * 1024 + q] = p;
        pb[j] = f2bf(p);
    }
    u16* trow = attnT + (long long)blockIdx.y * tBatchStride + (long long)q * 1024 + ky * 16;
    ((uint4*)trow)[0] = *(const uint4*)&pb[0];
    ((uint4*)trow)[1] = *(const uint4*)&pb[8];
}

// ---------------------------------------------------------------------------
__global__ void embed_kernel(const int* __restrict__ tok, const float* __restrict__ emb,
                             float* __restrict__ x, u16* __restrict__ xb)
{
    const int row = blockIdx.x;
    const int t   = tok[row];
    float4 v = ((const float4*)(emb + (long long)t * 1024))[threadIdx.x];
    ((float4*)(x + (long long)row * 1024))[threadIdx.x] = v;
    uint2 p;
    p.x = (u32)f2bf(v.x) | ((u32)f2bf(v.y) << 16);
    p.y = (u32)f2bf(v.z) | ((u32)f2bf(v.w) << 16);
    ((uint2*)(xb + (long long)row * 1024))[threadIdx.x] = p;
}

// ---------------------------------------------------------------------------
extern "C" void kernel_launch(void* const* d_in, const int* in_sizes, int n_in,
                              void* d_out, int out_size, void* d_ws, size_t ws_size,
                              hipStream_t stream)
{
    const int*   tok  = (const int*)d_in[0];
    const float* emb  = (const float*)d_in[1];
    const float* Wq   = (const float*)d_in[2];
    const float* bq   = (const float*)d_in[3];
    const float* Wk   = (const float*)d_in[4];
    const float* bk   = (const float*)d_in[5];
    const float* Wv   = (const float*)d_in[6];
    const float* bv   = (const float*)d_in[7];
    const float* Wm   = (const float*)d_in[8];
    const float* bm   = (const float*)d_in[9];
    const float* Wout = (const float*)d_in[10];
    const float* bout = (const float*)d_in[11];
    float* out = (float*)d_out;

    constexpr int B = 8, S = 1024, H = 1024, V = 512, L = 6;
    constexpr long long M = (long long)B * S;  // 8192

    char* ws = (char*)d_ws;
    u16*   WqkvT = (u16*)ws;   ws += (long long)L * 3 * H * H * 2;  // [L][3H][H]
    u16*   WmT   = (u16*)ws;   ws += (long long)L * H * H * 2;      // [L][H][H]
    u16*   WoutT = (u16*)ws;   ws += (long long)V * H * 2;          // [V][H]
    float* bqkv  = (float*)ws; ws += (long long)L * 3 * H * 4;      // [L][3H]
    float* x     = (float*)ws; ws += M * H * 4;                     // residual f32
    u16*   xb    = (u16*)ws;   ws += M * H * 2;                     // residual bf16
    u16*   QKV   = (u16*)ws;   ws += M * 3 * H * 2;                 // [M][3H]
    u16*   attnT = (u16*)ws;   ws += (long long)B * S * S * 2;      // [b][q][k]
    u16*   Vt    = (u16*)ws;   ws += (long long)B * S * S * 2;      // [b][h][s]
    u16*   ctxb  = (u16*)ws;   ws += M * H * 2;                     // [M][H]

    float* attnOut = out + (long long)B * S * V;  // [L][B][S(key)][S(query)]

    setup_weights<L, H, V><<<dim3(16, 16, 4 * L + 2), dim3(64, 4), 0, stream>>>(
        Wq, Wk, Wv, Wm, Wout, bq, bk, bv, WqkvT, WmT, WoutT, bqkv);
    embed_kernel<<<M, 256, 0, stream>>>(tok, emb, x, xb);

    for (int l = 0; l < L; ++l) {
        // QKV = xb @ [Wq|Wk|Wv] + bias  -> bf16 [M][3H]
        gemm_bt<EPI_QKV><<<dim3(3 * H / 128, M / 128, 1), 256, 0, stream>>>(
            xb, H, 0, WqkvT + (long long)l * 3 * H * H, H, 0,
            QKV, 3 * H, 0, H, bqkv + l * 3 * H, nullptr, nullptr, nullptr, 0.f);

        // logits[k,q] = K . Q * scale + mask  (lower-triangle tiles only)
        float* attnL = attnOut + (long long)l * B * S * S;
        gemm_bt<EPI_LOGITS><<<dim3(36, 1, B), 256, 0, stream>>>(
            QKV + H, 3 * H, (long long)S * 3 * H,
            QKV, 3 * H, (long long)S * 3 * H,
            attnL, S, (long long)S * S, H,
            nullptr, nullptr, nullptr, nullptr, 0.03125f);

        // softmax over k (causal-aware) + emit attnT bf16 [b][q][k]
        softmax_emit<<<dim3(S / 16, B), dim3(16, 64), 0, stream>>>(
            attnL, (long long)S * S, attnT, (long long)S * S);

        // V [s,h] -> Vt [h,s] bf16
        transpose_bf16<u16><<<dim3(16, 16, B), dim3(64, 4), 0, stream>>>(
            QKV + 2 * H, 3 * H, (long long)S * 3 * H, Vt, S, (long long)S * S);

        // ctx[q,h] = sum_{k<=q} attnT[q,k] * Vt[h,k]  -> bf16 (K truncated)
        gemm_bt<EPI_CTX><<<dim3(H / 128, S / 128, B), 256, 0, stream>>>(
            attnT, S, (long long)S * S, Vt, S, (long long)S * S,
            ctxb, H, (long long)S * H, S,
            nullptr, nullptr, nullptr, nullptr, 0.f);

        // x = x + ctx + relu(ctx @ Wm + bm); xb = bf16(x)
        gemm_bt<EPI_MLP><<<dim3(H / 128, M / 128, 1), 256, 0, stream>>>(
            ctxb, H, 0, WmT + (long long)l * H * H, H, 0,
            nullptr, H, 0, H, bm + l * H, x, ctxb, xb, 0.f);
    }

    // out = xb @ Wout + bout  -> f32
    gemm_bt<EPI_OUT><<<dim3(V / 128, M / 128, 1), 256, 0, stream>>>(
        xb, H, 0, WoutT, H, 0, out, V, 0, H,
        bout, nullptr, nullptr, nullptr, 0.f);
}

// Round 4
// 1355.179 us; speedup vs baseline: 1.3577x; 1.0995x over previous
//
#include <hip/hip_runtime.h>
#include <stdint.h>

typedef unsigned short u16;
typedef unsigned int u32;
typedef __bf16 bf16x8 __attribute__((ext_vector_type(8)));
typedef float floatx4 __attribute__((ext_vector_type(4)));

#define NEG_INF_F (-10000000.0f)

__device__ __forceinline__ float bf2f(u16 u) {
    union { u32 u; float f; } x; x.u = ((u32)u) << 16; return x.f;
}
__device__ __forceinline__ u16 f2bf(float f) {
    union { float f; u32 u; } x; x.f = f;
    u32 r = x.u + 0x7fffu + ((x.u >> 16) & 1u);   // RNE
    return (u16)(r >> 16);
}

__device__ __forceinline__ void async_cp16(const void* g, void* l) {
    __builtin_amdgcn_global_load_lds(
        (const __attribute__((address_space(1))) void*)g,
        (__attribute__((address_space(3))) void*)l, 16, 0, 0);
}

// ---------------------------------------------------------------------------
// BT GEMM: C[m,n] = sum_k A[m,k] * B[n,k]
// 128x128 tile, 256 threads (4 waves 2x2), mfma_f32_16x16x32_bf16, BK=64,
// global_load_lds width-16 staging + 16B-group XOR swizzle (conflict-free).
// All grids are 1D with XCD-aware decode (block i -> XCD i&7 assumed):
//   z=1 EPIs (QKV/MLP/OUT): XCD k owns x-tiles [k*nx/8, (k+1)*nx/8); same-y
//     blocks adjacent so the A-tile is reused while L2-hot. (nx==4: k>>1.)
//   LOGITS/CTX: XCD k owns batch k (4 MB K/Q or attnT/Vt set fits its L2).
// EPI_LOGITS: triangular t -> only k-tile <= q-tile computed.
// EPI_CTX:    Keff = min(K, (q_tile+1)*128) (attnT zero beyond q).
// ---------------------------------------------------------------------------
enum { EPI_QKV = 0, EPI_LOGITS = 1, EPI_CTX = 2, EPI_MLP = 3, EPI_OUT = 4 };

template <int EPI>
__global__ __launch_bounds__(256) void gemm_bt(
    const u16* __restrict__ A, int lda, long long aBatch,
    const u16* __restrict__ B, int ldb, long long bBatch,
    void* __restrict__ Cv, int ldc, long long cBatch,
    int K,
    const float* __restrict__ bias,
    const u16* __restrict__ ctxb,      // EPI_MLP: ctx bf16 (read)
    u16* __restrict__ xb,              // EPI_MLP: bf16 residual (read+write)
    float scale, int nx, int ny)
{
    __shared__ __align__(16) u16 sA[128 * 64];   // 16 KB
    __shared__ __align__(16) u16 sB[128 * 64];   // 16 KB

    const int tid  = threadIdx.x;
    const int wave = tid >> 6;
    const int lane = tid & 63;

    int bxE, byE, bz;
    if constexpr (EPI == EPI_LOGITS) {
        bz = blockIdx.x & 7;
        int t = blockIdx.x >> 3;                       // 0..35 triangular
        int tq = (int)((sqrtf(8.0f * t + 1.0f) - 1.0f) * 0.5f);
        while ((tq + 1) * (tq + 2) / 2 <= t) ++tq;
        while (tq * (tq + 1) / 2 > t) --tq;
        bxE = tq;                       // n-tile = query
        byE = t - tq * (tq + 1) / 2;    // m-tile = key (<= tq)
    } else if constexpr (EPI == EPI_CTX) {
        bz = blockIdx.x & 7;
        int t = blockIdx.x >> 3;        // 0..63
        bxE = t & 7;                    // h-tile
        byE = t >> 3;                   // q-tile
    } else {
        bz = 0;
        const int k = blockIdx.x & 7, r = blockIdx.x >> 3;
        if (nx >= 8) { const int xp = nx >> 3; bxE = xp * k + (r % xp); byE = r / xp; }
        else         { bxE = k >> 1; byE = (k & 1) * (ny >> 1) + r; }
    }
    int Keff = K;
    if constexpr (EPI == EPI_CTX) Keff = min(K, (byE + 1) * 128);

    const u16* Ab = A + (long long)bz * aBatch + (long long)(byE * 128) * lda;
    const u16* Bb = B + (long long)bz * bBatch + (long long)(bxE * 128) * ldb;

    const int wm = wave >> 1, wn = wave & 1;
    const int quad = lane >> 4;

    // staging: 16 calls/matrix, call c covers rows c*8..c*8+7 (8 lanes/row).
    const int srowoff = lane >> 3;
    const int gf      = (lane & 7) ^ ((lane >> 3) & 7);

    const int ra = 64 * wm + (lane & 15);
    const int rb = 64 * wn + (lane & 15);
    const int rx7 = lane & 7;

    floatx4 zero = {0.f, 0.f, 0.f, 0.f};
    floatx4 acc[4][4];
#pragma unroll
    for (int i = 0; i < 4; ++i)
#pragma unroll
        for (int j = 0; j < 4; ++j) acc[i][j] = zero;

    for (int k0 = 0; k0 < Keff; k0 += 64) {
#pragma unroll
        for (int i = 0; i < 4; ++i) {
            const int c = wave * 4 + i;
            const int r = c * 8 + srowoff;
            async_cp16(Ab + (long long)r * lda + k0 + gf * 8, &sA[c * 512 + lane * 8]);
            async_cp16(Bb + (long long)r * ldb + k0 + gf * 8, &sB[c * 512 + lane * 8]);
        }
        __syncthreads();

#pragma unroll
        for (int kk = 0; kk < 64; kk += 32) {
            const int gbase = kk >> 3;
            const int ga = ((gbase + quad) ^ rx7) << 3;
            bf16x8 af[4], bf[4];
#pragma unroll
            for (int mi = 0; mi < 4; ++mi)
                af[mi] = *(const bf16x8*)&sA[(ra + 16 * mi) * 64 + ga];
#pragma unroll
            for (int ni = 0; ni < 4; ++ni)
                bf[ni] = *(const bf16x8*)&sB[(rb + 16 * ni) * 64 + ga];
#pragma unroll
            for (int mi = 0; mi < 4; ++mi)
#pragma unroll
                for (int ni = 0; ni < 4; ++ni)
                    acc[mi][ni] = __builtin_amdgcn_mfma_f32_16x16x32_bf16(
                        af[mi], bf[ni], acc[mi][ni], 0, 0, 0);
        }
        __syncthreads();
    }

    // epilogue: C/D layout col = lane&15, row = (lane>>4)*4 + reg  [m89-verified]
    const int m0 = byE * 128 + 64 * wm + (quad << 2);
    const int n0 = bxE * 128 + 64 * wn + (lane & 15);
#pragma unroll
    for (int mi = 0; mi < 4; ++mi) {
#pragma unroll
        for (int ni = 0; ni < 4; ++ni) {
            const int gn = n0 + ni * 16;
#pragma unroll
            for (int r = 0; r < 4; ++r) {
                const int gm = m0 + mi * 16 + r;
                float v = acc[mi][ni][r];
                if constexpr (EPI == EPI_QKV) {
                    v += bias[gn];
                    ((u16*)Cv)[(long long)gm * ldc + gn] = f2bf(v);
                } else if constexpr (EPI == EPI_LOGITS) {
                    v = v * scale + (gm > gn ? NEG_INF_F : 0.0f);  // m=key, n=query
                    ((float*)Cv)[(long long)bz * cBatch + (long long)gm * ldc + gn] = v;
                } else if constexpr (EPI == EPI_CTX) {
                    ((u16*)Cv)[(long long)bz * cBatch + (long long)gm * ldc + gn] = f2bf(v);
                } else if constexpr (EPI == EPI_MLP) {
                    const long long idx = (long long)gm * ldc + gn;
                    v += bias[gn];
                    v = fmaxf(v, 0.0f);
                    float xv = bf2f(xb[idx]) + bf2f(ctxb[idx]) + v;  // x + ctx + relu
                    xb[idx] = f2bf(xv);
                } else {  // EPI_OUT
                    v += bias[gn];
                    ((float*)Cv)[(long long)gm * ldc + gn] = v;
                }
            }
        }
    }
}

// ---------------------------------------------------------------------------
// Setup mega-kernel: weight transposes (f32->bf16) + bias packing.
// Grid (16,16, 4L+2), block (64,4). See zone map in round-2 version.
// ---------------------------------------------------------------------------
template <int L, int H, int V>
__global__ void setup_weights(const float* __restrict__ Wq, const float* __restrict__ Wk,
                              const float* __restrict__ Wv, const float* __restrict__ Wm,
                              const float* __restrict__ Wout,
                              const float* __restrict__ bq, const float* __restrict__ bk,
                              const float* __restrict__ bv,
                              u16* __restrict__ WqkvT, u16* __restrict__ WmT,
                              u16* __restrict__ WoutT, float* __restrict__ bqkv)
{
    const int z = blockIdx.z;
    if (z == 4 * L + 1) {
        int i = ((blockIdx.y * 16 + blockIdx.x) * 256) + threadIdx.y * 64 + threadIdx.x;
        if (i < L * 3 * H) {
            int l = i / (3 * H), j = i % (3 * H);
            float v = (j < H) ? bq[l * H + j]
                    : (j < 2 * H) ? bk[l * H + j - H]
                                  : bv[l * H + j - 2 * H];
            bqkv[i] = v;
        }
        return;
    }

    const float* in;
    u16* outp;
    int inStride, outStride;
    if (z == 4 * L) {
        if (blockIdx.x >= V / 64) return;
        in = Wout; inStride = V;
        outp = WoutT; outStride = H;
    } else {
        const int which = z / L, l = z % L;
        inStride = H; outStride = H;
        if (which == 3) { in = Wm + (long long)l * H * H; outp = WmT + (long long)l * H * H; }
        else {
            in   = (which == 0 ? Wq : which == 1 ? Wk : Wv) + (long long)l * H * H;
            outp = WqkvT + (long long)l * 3 * H * H + (long long)which * H * H;
        }
    }

    __shared__ float tile[64][65];
    const int r0 = blockIdx.y * 64, c0 = blockIdx.x * 64;
    const int x = threadIdx.x, y = threadIdx.y;
#pragma unroll
    for (int j = 0; j < 16; ++j) {
        int r = y + j * 4;
        tile[r][x] = in[(long long)(r0 + r) * inStride + c0 + x];
    }
    __syncthreads();
#pragma unroll
    for (int j = 0; j < 16; ++j) {
        int r = y + j * 4;
        outp[(long long)(c0 + r) * outStride + r0 + x] = f2bf(tile[x][r]);
    }
}

// ---------------------------------------------------------------------------
// Merged attention post-processing. Grid (64, 16), block (16,64) = 1024 thr.
//  zone = blockIdx.y < 8 : causal column-softmax over k for batch=zone,
//    in-place probs (f32, exact zeros for k>q) + attnT bf16 [q][k] emission.
//  zone >= 8 : V [s, 2H+h] -> Vt [h][s] bf16 transpose for batch zone-8
//    (4 64x64 tiles per block, threads reinterpreted as (64,16)).
// ---------------------------------------------------------------------------
__global__ __launch_bounds__(1024) void attn_post(
    float* __restrict__ attn, long long aStride,
    u16* __restrict__ attnT, long long tStride,
    const u16* __restrict__ qkv, u16* __restrict__ Vt)
{
    const int zone = blockIdx.y;
    if (zone < 8) {
        __shared__ float sm[64][16], sl[64][16], sm2[8][16], sl2[8][16];
        __shared__ float sM[16], sInv[16];

        float* base = attn + (long long)zone * aStride;
        const int x = threadIdx.x, ky = threadIdx.y;
        const int q = blockIdx.x * 16 + x;

        float v[16];
        float m = -3.4e38f, l = 0.f;
#pragma unroll
        for (int j = 0; j < 16; ++j) {
            const int k = ky * 16 + j;
            float vj = NEG_INF_F;
            if (k <= q) vj = base[(long long)k * 1024 + q];
            v[j] = vj;
            float mn = fmaxf(m, vj);
            l = l * __expf(m - mn) + __expf(vj - mn);
            m = mn;
        }
        sm[ky][x] = m;
        sl[ky][x] = l;
        __syncthreads();
        if (ky < 8) {
            float M = -3.4e38f, L = 0.f;
#pragma unroll
            for (int t = 0; t < 8; ++t) {
                float mm = sm[ky + 8 * t][x], ll = sl[ky + 8 * t][x];
                float mn = fmaxf(M, mm);
                L = L * __expf(M - mn) + ll * __expf(mm - mn);
                M = mn;
            }
            sm2[ky][x] = M;
            sl2[ky][x] = L;
        }
        __syncthreads();
        if (ky == 0) {
            float M = -3.4e38f, L = 0.f;
#pragma unroll
            for (int t = 0; t < 8; ++t) {
                float mm = sm2[t][x], ll = sl2[t][x];
                float mn = fmaxf(M, mm);
                L = L * __expf(M - mn) + ll * __expf(mm - mn);
                M = mn;
            }
            sM[x]   = M;
            sInv[x] = 1.0f / L;
        }
        __syncthreads();
        const float M = sM[x], inv = sInv[x];

        u16 pb[16];
#pragma unroll
        for (int j = 0; j < 16; ++j) {
            float p = __expf(v[j] - M) * inv;   // masked: underflows to exact 0
            base[(long long)(ky * 16 + j) * 1024 + q] = p;
            pb[j] = f2bf(p);
        }
        u16* trow = attnT + (long long)zone * tStride + (long long)q * 1024 + ky * 16;
        ((uint4*)trow)[0] = *(const uint4*)&pb[0];
        ((uint4*)trow)[1] = *(const uint4*)&pb[8];
    } else {
        const int b = zone - 8;
        const u16* Vb = qkv + 2 * 1024 + (long long)b * (1024LL * 3072);
        u16* Ob       = Vt + (long long)b * (1024LL * 1024);
        __shared__ float tile[64][65];
        const int tid = threadIdx.y * 16 + threadIdx.x;
        const int tx = tid & 63, ty = tid >> 6;   // (64,16) view
#pragma unroll
        for (int rep = 0; rep < 4; ++rep) {
            const int T = blockIdx.x + rep * 64;  // 0..255
            const int s0 = (T >> 4) * 64, h0 = (T & 15) * 64;
            __syncthreads();
#pragma unroll
            for (int j = 0; j < 4; ++j) {
                const int s = j * 16 + ty;
                tile[s][tx] = bf2f(Vb[(long long)(s0 + s) * 3072 + h0 + tx]);
            }
            __syncthreads();
#pragma unroll
            for (int j = 0; j < 4; ++j) {
                const int h = j * 16 + ty;
                Ob[(long long)(h0 + h) * 1024 + s0 + tx] = f2bf(tile[tx][h]);
            }
        }
    }
}

// ---------------------------------------------------------------------------
__global__ void embed_kernel(const int* __restrict__ tok, const float* __restrict__ emb,
                             u16* __restrict__ xb)
{
    const int row = blockIdx.x;
    const int t   = tok[row];
    float4 v = ((const float4*)(emb + (long long)t * 1024))[threadIdx.x];
    uint2 p;
    p.x = (u32)f2bf(v.x) | ((u32)f2bf(v.y) << 16);
    p.y = (u32)f2bf(v.z) | ((u32)f2bf(v.w) << 16);
    ((uint2*)(xb + (long long)row * 1024))[threadIdx.x] = p;
}

// ---------------------------------------------------------------------------
extern "C" void kernel_launch(void* const* d_in, const int* in_sizes, int n_in,
                              void* d_out, int out_size, void* d_ws, size_t ws_size,
                              hipStream_t stream)
{
    const int*   tok  = (const int*)d_in[0];
    const float* emb  = (const float*)d_in[1];
    const float* Wq   = (const float*)d_in[2];
    const float* bq   = (const float*)d_in[3];
    const float* Wk   = (const float*)d_in[4];
    const float* bk   = (const float*)d_in[5];
    const float* Wv   = (const float*)d_in[6];
    const float* bv   = (const float*)d_in[7];
    const float* Wm   = (const float*)d_in[8];
    const float* bm   = (const float*)d_in[9];
    const float* Wout = (const float*)d_in[10];
    const float* bout = (const float*)d_in[11];
    float* out = (float*)d_out;

    constexpr int B = 8, S = 1024, H = 1024, V = 512, L = 6;
    constexpr long long M = (long long)B * S;  // 8192

    char* ws = (char*)d_ws;
    u16*   WqkvT = (u16*)ws;   ws += (long long)L * 3 * H * H * 2;  // [L][3H][H]
    u16*   WmT   = (u16*)ws;   ws += (long long)L * H * H * 2;      // [L][H][H]
    u16*   WoutT = (u16*)ws;   ws += (long long)V * H * 2;          // [V][H]
    float* bqkv  = (float*)ws; ws += (long long)L * 3 * H * 4;      // [L][3H]
    u16*   xb    = (u16*)ws;   ws += M * H * 2;                     // residual bf16
    u16*   QKV   = (u16*)ws;   ws += M * 3 * H * 2;                 // [M][3H]
    u16*   attnT = (u16*)ws;   ws += (long long)B * S * S * 2;      // [b][q][k]
    u16*   Vt    = (u16*)ws;   ws += (long long)B * S * S * 2;      // [b][h][s]
    u16*   ctxb  = (u16*)ws;   ws += M * H * 2;                     // [M][H]

    float* attnOut = out + (long long)B * S * V;  // [L][B][S(key)][S(query)]

    setup_weights<L, H, V><<<dim3(16, 16, 4 * L + 2), dim3(64, 4), 0, stream>>>(
        Wq, Wk, Wv, Wm, Wout, bq, bk, bv, WqkvT, WmT, WoutT, bqkv);
    embed_kernel<<<M, 256, 0, stream>>>(tok, emb, xb);

    for (int l = 0; l < L; ++l) {
        // QKV = xb @ [Wq|Wk|Wv] + bias  -> bf16 [M][3H]
        gemm_bt<EPI_QKV><<<1536, 256, 0, stream>>>(
            xb, H, 0, WqkvT + (long long)l * 3 * H * H, H, 0,
            QKV, 3 * H, 0, H, bqkv + l * 3 * H, nullptr, nullptr, 0.f, 24, 64);

        // logits[k,q] = K . Q * scale + mask  (lower-triangle tiles, batch/XCD)
        float* attnL = attnOut + (long long)l * B * S * S;
        gemm_bt<EPI_LOGITS><<<288, 256, 0, stream>>>(
            QKV + H, 3 * H, (long long)S * 3 * H,
            QKV, 3 * H, (long long)S * 3 * H,
            attnL, S, (long long)S * S, H,
            nullptr, nullptr, nullptr, 0.03125f, 0, 0);

        // softmax+attnT emission (zones 0-7) and V->Vt transpose (zones 8-15)
        attn_post<<<dim3(64, 16), dim3(16, 64), 0, stream>>>(
            attnL, (long long)S * S, attnT, (long long)S * S, QKV, Vt);

        // ctx[q,h] = sum_{k<=q} attnT[q,k] * Vt[h,k]  -> bf16 (batch/XCD)
        gemm_bt<EPI_CTX><<<512, 256, 0, stream>>>(
            attnT, S, (long long)S * S, Vt, S, (long long)S * S,
            ctxb, H, (long long)S * H, S,
            nullptr, nullptr, nullptr, 0.f, 0, 0);

        // xb = bf16( xb + ctx + relu(ctx @ Wm + bm) )
        gemm_bt<EPI_MLP><<<512, 256, 0, stream>>>(
            ctxb, H, 0, WmT + (long long)l * H * H, H, 0,
            nullptr, H, 0, H, bm + l * H, ctxb, xb, 0.f, 8, 64);
    }

    // out = xb @ Wout + bout  -> f32
    gemm_bt<EPI_OUT><<<256, 256, 0, stream>>>(
        xb, H, 0, WoutT, H, 0, out, V, 0, H,
        bout, nullptr, nullptr, 0.f, 4, 64);
}